// Round 13
// baseline (323.356 us; speedup 1.0000x reference)
//
#include <hip/hip_runtime.h>

#define S_LEN 2048
#define HID 4096
#define NH 32
#define NKV 8
#define HD 128
#define KVW 1024       // NKV*HD
#define NQKV 6144      // HID + 2*KVW

typedef _Float16 f16;
typedef _Float16 f16x8 __attribute__((ext_vector_type(8)));
typedef _Float16 f16x4 __attribute__((ext_vector_type(4)));
typedef float f32x4 __attribute__((ext_vector_type(4)));
typedef float f32x16 __attribute__((ext_vector_type(16)));
typedef unsigned int u32;
typedef u32 u32x4 __attribute__((ext_vector_type(4)));

__device__ __forceinline__ void gll16(const void* g, void* lds) {
  __builtin_amdgcn_global_load_lds((const __attribute__((address_space(1))) void*)g,
                                   (__attribute__((address_space(3))) void*)lds, 16, 0, 0);
}

template<int N> __device__ __forceinline__ void vmwait() {
  if constexpr (N == 0) asm volatile("s_waitcnt vmcnt(0)" ::: "memory");
  else if constexpr (N == 2) asm volatile("s_waitcnt vmcnt(2)" ::: "memory");
  else if constexpr (N == 3) asm volatile("s_waitcnt vmcnt(3)" ::: "memory");
  else if constexpr (N == 4) asm volatile("s_waitcnt vmcnt(4)" ::: "memory");
  else if constexpr (N == 5) asm volatile("s_waitcnt vmcnt(5)" ::: "memory");
  else if constexpr (N == 6) asm volatile("s_waitcnt vmcnt(6)" ::: "memory");
  else if constexpr (N == 7) asm volatile("s_waitcnt vmcnt(7)" ::: "memory");
  else if constexpr (N == 8) asm volatile("s_waitcnt vmcnt(8)" ::: "memory");
  else static_assert(N == 0, "add vmcnt case");
}
#define LGKM0 asm volatile("s_waitcnt lgkmcnt(0)" ::: "memory")
#define BAR() __builtin_amdgcn_s_barrier()

// ---------------- fused prep: weight transpose+cast (wprep) + hidden cast + trig ----------------
// grid = 40960 (wprep) + 4096 (cast) + 512 (trig) = 45568 blocks x 256 thr.
__global__ __launch_bounds__(256) void k_prep(
    const float* __restrict__ hs, const float* __restrict__ wq,
    const float* __restrict__ wk, const float* __restrict__ wv,
    const float* __restrict__ wo,
    f16* __restrict__ Hh, f16* __restrict__ Wt, f16* __restrict__ Wot,
    float4* __restrict__ trig)
{
  __shared__ float tile[32][33];
  int bid = blockIdx.x;
  int t = threadIdx.x;
  if (bid >= 40960) {
    int b2 = bid - 40960;
    if (b2 < 4096) {      // cast hidden f32 -> f16, 8 elems/thread
      size_t i = ((size_t)b2 * 256 + t) * 8;
      float4 a = *(const float4*)(hs + i);
      float4 b = *(const float4*)(hs + i + 4);
      f16x8 o = { (f16)a.x, (f16)a.y, (f16)a.z, (f16)a.w,
                  (f16)b.x, (f16)b.y, (f16)b.z, (f16)b.w };
      *(f16x8*)(Hh + i) = o;
    } else {              // trig table
      int id = (b2 - 4096) * 256 + t;
      int s = id >> 6, i = id & 63;
      float f0 = powf(10000.f, -(float)((2 * i) & 63) / 64.f);
      float f1 = powf(10000.f, -(float)((2 * i + 1) & 63) / 64.f);
      float a0 = (float)s * f0, a1 = (float)s * f1;
      trig[id] = make_float4(cosf(a0), cosf(a1), sinf(a0), sinf(a1));
    }
    return;
  }
  const float* src; f16* dst; int N; int r;
  if (bid < 16384)      { src = wq; dst = Wt;                          N = 4096; r = bid; }
  else if (bid < 20480) { src = wk; dst = Wt + (size_t)4096 * 4096;    N = 1024; r = bid - 16384; }
  else if (bid < 24576) { src = wv; dst = Wt + (size_t)5120 * 4096;    N = 1024; r = bid - 20480; }
  else                  { src = wo; dst = Wot;                         N = 4096; r = bid - 24576; }
  int tpr = N >> 5;
  int kb = (r / tpr) * 32, nb = (r % tpr) * 32;
  {
    int kl = t >> 3, ng = t & 7;
    float4 v = *(const float4*)(src + (size_t)(kb + kl) * N + nb + ng * 4);
    tile[kl][ng * 4 + 0] = v.x; tile[kl][ng * 4 + 1] = v.y;
    tile[kl][ng * 4 + 2] = v.z; tile[kl][ng * 4 + 3] = v.w;
  }
  __syncthreads();
  {
    int nl = t >> 3, kg = t & 7;
    f16x4 o = { (f16)tile[kg * 4 + 0][nl], (f16)tile[kg * 4 + 1][nl],
                (f16)tile[kg * 4 + 2][nl], (f16)tile[kg * 4 + 3][nl] };
    *(f16x4*)(dst + (size_t)(nb + nl) * HID + kb + kg * 4) = o;
  }
}

extern __shared__ char smem[];

// ---------------- 8-phase k-half-staggered GEMM, 3rd port (R6/R8 bugs fixed) ----------------
// BM=256, BN=192 (grid 32x8=256, FULL fill - R8 bug#1 fixed), BK=64, 512 thr = 8 waves
// (2M x 4N), wave out 128x48, NT=64.
// LDS 136KB: A = 4-ring of k-half slots [256 rows][32 k] (16KB, 64B rows) @0;
//            B = 3-ring of full tiles [192][64] (24KB, 128B rows) @64KB.
// Swizzles: A 64B rows: granule g(16B) of row r holds global granule g^((r>>1)&3)
//   -> frag read (rows base+la, col lg): 8 distinct bank-starts x 2 lanes at
//   DIFFERENT addresses = 2-way = free (R8 bug#2: (r>>2)&3 gave 4-way, 9.4M confl).
//   B 128B rows: g^(r&7) - R5-proven 0 conflicts.
// Cadence (>=6-phase prefetch lead everywhere - R6 bug: B had only 1-2):
//   p1: ld A(t,k0,m0)+B(t,k0) | stage A(t+1,k1)          [read t+1.p3: 6-ph lead]
//   p2: ld A(t,k0,m1)         | stage B(t+2)c0           [read t+2.p1: 7-ph lead]
//       MIDWAIT vmcnt(W_MID) before closing bar: drains A(t,k1) (staged t-1.p1)
//   p3: ld A(t,k1,m0)+B(t,k1) | stage A(t+2,k0)+B(t+2)c1 [reads t+2: 6-ph lead]
//   p4: ld A(t,k1,m1)         | stage B(t+2)c2
//       ENDWAIT vmcnt(W_END): drains all t-1 issues (t's needs), keeps t's 7 in flight
// Per-wave queue arithmetic: TI = 4+BCALLS call-sites/tile; W_END = TI; W_MID = TI+1.
// Slot liveness: A(t+2,k0) slot == A(t,k0), staged t.p3 after last read t.p2 (bar'd);
//   A(t+1,k1) slot == A(t-1,k1), read (t-1).p4; B(t+2) slot == B(t-1), read (t-1).p3.
// Each phase: ds_reads | stages | BAR | lgkm0 | setprio1 | 12 MFMA | setprio0 | BAR.
__global__ __launch_bounds__(512, 2) void k_gemm8(
    const f16* __restrict__ A, const f16* __restrict__ Bt,
    f16* __restrict__ Qr, f16* __restrict__ Kr, f16* __restrict__ Vt,
    const float4* __restrict__ trig)
{
  constexpr int BN = 192;
  constexpr int NF = 3;                 // B frags / wave / k-half
  constexpr int BCALLS = BN / 64;       // 3 staging calls per B tile
  constexpr int BBYTES = BN * 128;      // 24KB
  constexpr int TI = 4 + BCALLS;        // 7 call-sites per tile
  constexpr int W_END = TI, W_MID = TI + 1;
  constexpr int NT = 64;

  const int tid = threadIdx.x, ln = tid & 63, w = tid >> 6;
  const int la = ln & 15, lg = ln >> 4;
  const int wr = w >> 2, wc = w & 3;

  // XCD-compact block mapping (R11-verified)
  int bx, by;
  {
    int b = blockIdx.y * gridDim.x + blockIdx.x;
    int cx = gridDim.x >> 3;
    int xcd = b & 7, rr = b >> 3;
    bx = xcd * cx + (rr % cx);
    by = rr / cx;
  }
  const int m0 = by * 256, n0 = bx * BN;

  // staging bases
  const char* asrcA[2];                 // A half-stage call c (rows c*128+..)
#pragma unroll
  for (int c = 0; c < 2; ++c) {
    int row = c * 128 + (tid >> 2);
    int sg = (tid & 3) ^ ((row >> 1) & 3);
    asrcA[c] = (const char*)A + ((size_t)(m0 + row) * HID) * 2 + (size_t)sg * 16;
  }
  const char* bsrcB[BCALLS];
#pragma unroll
  for (int c = 0; c < BCALLS; ++c) {
    int row = c * 64 + (tid >> 3);
    int g = (tid & 7) ^ (row & 7);
    bsrcB[c] = (const char*)Bt + ((size_t)(n0 + row) * HID) * 2 + (size_t)g * 16;
  }
  char* const Bbase = smem + 65536;
  const int d16 = tid * 16;

  auto stA = [&](int t, int h) {        // 2 call-sites
    char* b = smem + (((2 * t + h) & 3) * 16384) + d16;
    size_t off = (size_t)t * 128 + h * 64;
    gll16(asrcA[0] + off, b); gll16(asrcA[1] + off, b + 8192);
  };
  auto stB = [&](int t, int c) {        // 1 call-site
    char* b = Bbase + (t % 3) * BBYTES + c * 8192 + d16;
    gll16(bsrcB[c] + (size_t)t * 128, b);
  };
  f16x8 af[4], bf[NF];
  auto ldA = [&](int t, int mh, int ks) {
    const char* sb = smem + (((2 * t + ks) & 3) * 16384);
#pragma unroll
    for (int i = 0; i < 4; ++i) {
      int rl = wr * 128 + mh * 64 + i * 16 + la;
      af[i] = *(const f16x8*)(sb + rl * 64 + ((lg ^ ((rl >> 1) & 3)) * 16));
    }
  };
  auto ldB = [&](int t, int ks) {
    const char* sb = Bbase + (t % 3) * BBYTES;
#pragma unroll
    for (int n = 0; n < NF; ++n) {
      int rb = wc * (NF * 16) + n * 16 + la;
      bf[n] = *(const f16x8*)(sb + rb * 128 + (((ks * 4 + lg) ^ (rb & 7)) * 16));
    }
  };

  f32x4 acc[8][NF] = {};

#define MM12(MH)                                                                      \
  __builtin_amdgcn_s_setprio(1);                                                      \
  _Pragma("unroll")                                                                   \
  for (int i = 0; i < 4; ++i)                                                         \
    _Pragma("unroll")                                                                 \
    for (int n = 0; n < NF; ++n)                                                      \
      acc[(MH)*4 + i][n] =                                                            \
        __builtin_amdgcn_mfma_f32_16x16x32_f16(af[i], bf[n], acc[(MH)*4 + i][n], 0, 0, 0); \
  __builtin_amdgcn_s_setprio(0);

  // prologue: A(0,k0) A(0,k1) B(0) A(1,k0) B(1); drain first 3 groups, keep 5 in flight
  stA(0, 0); stA(0, 1);
  for (int c = 0; c < BCALLS; ++c) stB(0, c);
  stA(1, 0);
  for (int c = 0; c < BCALLS; ++c) stB(1, c);
  vmwait<BCALLS + 2>();
  BAR();

  for (int t = 0; t < NT; ++t) {
    // ---- p1: (m0, k0) ----
    ldA(t, 0, 0); ldB(t, 0);
    if (t + 1 < NT) stA(t + 1, 1);
    BAR(); LGKM0;
    MM12(0);
    BAR();
    // ---- p2: (m1, k0) ----
    ldA(t, 1, 0);
    if (t + 2 < NT) stB(t + 2, 0);
    BAR(); LGKM0;
    MM12(1);
    if (t < NT - 2) vmwait<W_MID>(); else vmwait<0>();
    BAR();
    // ---- p3: (m0, k1) ----
    ldA(t, 0, 1); ldB(t, 1);
    if (t + 2 < NT) { stA(t + 2, 0); stB(t + 2, 1); }
    BAR(); LGKM0;
    MM12(0);
    BAR();
    // ---- p4: (m1, k1) ----
    ldA(t, 1, 1);
    if (t + 2 < NT) stB(t + 2, 2);
    BAR(); LGKM0;
    MM12(1);
    if (t < NT - 2) vmwait<W_END>(); else vmwait<0>();
    BAR();
  }
#undef MM12

  // ---- epilogue: RoPE -> Qr/Kr, V transposed -> Vt ----
#pragma unroll
  for (int mi = 0; mi < 8; ++mi) {
#pragma unroll
    for (int nf = 0; nf < NF; ++nf) {
      f32x4 fr = acc[mi][nf];
      int n = n0 + wc * (NF * 16) + nf * 16 + la;
      int mr = m0 + wr * 128 + mi * 16 + lg * 4;
      if (n < HID + KVW) {           // Q or K region -> RoPE
        int d = n & 127;
#pragma unroll
        for (int r = 0; r < 4; ++r) {
          float v = fr[r];
          float p = __shfl_xor(v, 1);
          float4 tc = trig[(size_t)(mr + r) * 64 + (d >> 1)];
          float cv = (d & 1) ? tc.y : tc.x;
          float sv = (d & 1) ? tc.w : tc.z;
          float o = v * cv + ((d & 1) ? p : -p) * sv;
          if (n < HID) Qr[(size_t)(mr + r) * HID + n] = (f16)o;
          else         Kr[(size_t)(mr + r) * KVW + (n - HID)] = (f16)o;
        }
      } else {                        // V region -> transposed store Vt[n][s]
        int nv = n - (HID + KVW);
        f16x4 o4 = { (f16)fr[0], (f16)fr[1], (f16)fr[2], (f16)fr[3] };
        *(f16x4*)(Vt + (size_t)nv * S_LEN + mr) = o4;
      }
    }
  }
}

// ---------------- loose-sync deep-prefetch GEMM (R12, kept for output projection) ----------------
template<int MODE, int MF, int NF, int WM, int WN>
__global__ __launch_bounds__(WM * WN * 64, 2) void k_gemm4(
    const f16* __restrict__ A, const f16* __restrict__ Bt,
    f16* __restrict__ Qr, f16* __restrict__ Kr, f16* __restrict__ Vt,
    const float4* __restrict__ trig, float* __restrict__ Cout)
{
  constexpr int NTHR = WM * WN * 64;
  constexpr int BM = WM * MF * 16;
  constexpr int BN = WN * NF * 16;
  constexpr int ABYTES = BM * 128;
  constexpr int BBYTES = BN * 128;
  constexpr int RPC = NTHR / 8;
  constexpr int ACALLS = BM / RPC;
  constexpr int BCALLS = BN / RPC;
  constexpr int NT = 64;

  const int tid = threadIdx.x, ln = tid & 63, w = tid >> 6;
  const int la = ln & 15, lg = ln >> 4;
  const int wr = w / WN, wc = w % WN;

  int bx, by;
  {
    int b = blockIdx.y * gridDim.x + blockIdx.x;
    int cx = gridDim.x >> 3;
    int xcd = b & 7, rr = b >> 3;
    bx = xcd * cx + (rr % cx);
    by = rr / cx;
  }
  const int m0 = by * BM, n0 = bx * BN;

  const char* asrc[ACALLS];
  const char* bsrc[BCALLS];
  int adst[ACALLS > BCALLS ? ACALLS : BCALLS];
#pragma unroll
  for (int c = 0; c < ACALLS; ++c) {
    int r = c * RPC + (tid >> 3);
    int g = (tid & 7) ^ (r & 7);
    asrc[c] = (const char*)A + ((size_t)(m0 + r) * HID + (size_t)g * 8) * 2;
    adst[c] = c * NTHR * 16 + tid * 16;
  }
#pragma unroll
  for (int c = 0; c < BCALLS; ++c) {
    int r = c * RPC + (tid >> 3);
    int g = (tid & 7) ^ (r & 7);
    bsrc[c] = (const char*)Bt + ((size_t)(n0 + (r >= BN ? r - BN : r)) * HID + (size_t)g * 8) * 2;
  }

  char* const Bbase = smem + 2 * ABYTES;
  f32x4 acc[MF][NF] = {};

#pragma unroll
  for (int c = 0; c < ACALLS; ++c) gll16(asrc[c], smem + adst[c]);
#pragma unroll
  for (int c = 0; c < BCALLS; ++c) gll16(bsrc[c], Bbase + adst[c]);
#pragma unroll
  for (int c = 0; c < BCALLS; ++c) gll16(bsrc[c] + 128, Bbase + 1 * BBYTES + adst[c]);
#pragma unroll
  for (int c = 0; c < BCALLS; ++c) gll16(bsrc[c] + 256, Bbase + 2 * BBYTES + adst[c]);
  vmwait<2 * BCALLS>();
  __builtin_amdgcn_s_barrier();

  for (int t = 0; t < NT; ++t) {
    if (t + 1 < NT) {
      char* sa = smem + ((t + 1) & 1) * ABYTES;
#pragma unroll
      for (int c = 0; c < ACALLS; ++c) gll16(asrc[c] + (size_t)(t + 1) * 128, sa + adst[c]);
    }
    if (t + 3 < NT) {
      char* sb = Bbase + ((t + 3) & 3) * BBYTES;
#pragma unroll
      for (int c = 0; c < BCALLS; ++c) gll16(bsrc[c] + (size_t)(t + 3) * 128, sb + adst[c]);
    }
    const char* sa = smem + (t & 1) * ABYTES;
    const char* sb = Bbase + (t & 3) * BBYTES;
#pragma unroll
    for (int ks = 0; ks < 2; ++ks) {
      f16x8 af[MF], bf[NF];
#pragma unroll
      for (int i = 0; i < MF; ++i) {
        int rl = wr * MF * 16 + i * 16 + la;
        af[i] = *(const f16x8*)(sa + rl * 128 + (((ks * 4 + lg) ^ (rl & 7)) * 16));
      }
#pragma unroll
      for (int n = 0; n < NF; ++n) {
        int rb = wc * NF * 16 + n * 16 + la;
        bf[n] = *(const f16x8*)(sb + rb * 128 + (((ks * 4 + lg) ^ (rb & 7)) * 16));
      }
      __builtin_amdgcn_s_setprio(1);
#pragma unroll
      for (int i = 0; i < MF; ++i)
#pragma unroll
        for (int n = 0; n < NF; ++n)
          acc[i][n] = __builtin_amdgcn_mfma_f32_16x16x32_f16(af[i], bf[n], acc[i][n], 0, 0, 0);
      __builtin_amdgcn_s_setprio(0);
    }
    if (t < NT - 3)      vmwait<BCALLS>();
    else if (t < NT - 1) vmwait<0>();
    if (t < NT - 1) __builtin_amdgcn_s_barrier();
  }

#pragma unroll
  for (int mi = 0; mi < MF; ++mi) {
#pragma unroll
    for (int nf = 0; nf < NF; ++nf) {
      f32x4 fr = acc[mi][nf];
      int n = n0 + wc * NF * 16 + nf * 16 + la;
      int mr = m0 + wr * MF * 16 + mi * 16 + lg * 4;
      if (MODE == 1) {
#pragma unroll
        for (int r = 0; r < 4; ++r)
          Cout[(size_t)(mr + r) * HID + n] = fr[r];
      }
    }
  }
}

// ---------------- flash attention, causal, GQA — swapped-QK^T 32x32 MFMA ----------------
#define KBYTES (64 * 128 * 2)   // 16KB K tile [64 kv][128 hd]
#define VBYTES (128 * 64 * 2)   // 16KB V tile [128 d][64 kv]

__global__ __launch_bounds__(256, 2) void k_attn(
    const f16* __restrict__ Qr, const f16* __restrict__ Kr, const f16* __restrict__ Vt,
    f16* __restrict__ AO)
{
  int bid = blockIdx.x;
  int h, c;
  if (bid < 256) { h = bid >> 3; c = bid & 7; }
  else           { int t = bid - 256; h = t >> 3; c = 15 - (t & 7); }
  const int hkv = h >> 2;
  const int q0c = c * 128;
  const int NT = 2 * c + 2;

  __shared__ char KV[2][KBYTES + VBYTES];

  const int tid = threadIdx.x;
  const int ln = tid & 63, w = tid >> 6;
  const int q = ln & 31;
  const int hi = ln >> 5;
  const int qg = q0c + w * 32 + q;

  size_t ksrc[4], vsrc[4];
  int kdo[4], vdo[4];
#pragma unroll
  for (int j = 0; j < 4; ++j) {
    int kc = w * 4 + j;
    int kr = kc * 4 + (ln >> 4);
    ksrc[j] = ((size_t)kr * KVW + hkv * HD) * 2 + (size_t)(((ln & 15) ^ (kr & 7)) * 16);
    kdo[j] = kc * 1024;
    int vc = w * 4 + j;
    int d = vc * 8 + (ln >> 3);
    vsrc[j] = ((size_t)(hkv * HD + d) * S_LEN) * 2 + (size_t)(((ln & 7) ^ (d & 7)) * 16);
    vdo[j] = KBYTES + vc * 1024;
  }

  f16x8 qf[8];
  {
    const f16* qrow = Qr + (size_t)qg * HID + h * HD + hi * 8;
#pragma unroll
    for (int ks = 0; ks < 8; ++ks) qf[ks] = *(const f16x8*)(qrow + ks * 16);
  }

  f32x16 ot[4] = {};
  float m2 = -3.0e38f, l = 0.f;
  const float K2 = 0.12753256471f;  // log2(e)/sqrt(128)

  int buf = 0;
#pragma unroll
  for (int j = 0; j < 4; ++j) {
    gll16((const char*)Kr + ksrc[j], &KV[0][kdo[j]]);
    gll16((const char*)Vt + vsrc[j], &KV[0][vdo[j]]);
  }

  for (int jt = 0; jt < NT; ++jt) {
    __syncthreads();
    if (jt + 1 < NT) {
      size_t ko = (size_t)(jt + 1) * 64 * KVW * 2;
      size_t vo = (size_t)(jt + 1) * 64 * 2;
#pragma unroll
      for (int j = 0; j < 4; ++j) {
        gll16((const char*)Kr + ksrc[j] + ko, &KV[buf ^ 1][kdo[j]]);
        gll16((const char*)Vt + vsrc[j] + vo, &KV[buf ^ 1][vdo[j]]);
      }
    }
    const int j0 = jt * 64;
    if (j0 <= q0c + w * 32 + 31) {
      const f16* Kb = (const f16*)&KV[buf][0];
      const f16* Vb = (const f16*)&KV[buf][KBYTES];
      f32x16 s0 = {}, s1 = {};
#pragma unroll
      for (int ks = 0; ks < 8; ++ks) {
        int cc = ((ks * 2 + hi) ^ (q & 7)) * 8;
        f16x8 k0 = *(const f16x8*)(Kb + q * 128 + cc);
        f16x8 k1 = *(const f16x8*)(Kb + (q + 32) * 128 + cc);
        s0 = __builtin_amdgcn_mfma_f32_32x32x16_f16(k0, qf[ks], s0, 0, 0, 0);
        s1 = __builtin_amdgcn_mfma_f32_32x32x16_f16(k1, qf[ks], s1, 0, 0, 0);
      }
      const bool nm = (j0 + 63 > q0c + w * 32);
      float p0[16], p1[16];
      float mx = -3.0e38f;
#pragma unroll
      for (int r = 0; r < 16; ++r) {
        float a = s0[r], b = s1[r];
        if (nm) {
          int kvb = j0 + (r & 3) + 8 * (r >> 2) + 4 * hi;
          if (kvb > qg) a = -3.0e38f;
          if (kvb + 32 > qg) b = -3.0e38f;
        }
        p0[r] = a; p1[r] = b;
        mx = fmaxf(mx, fmaxf(a, b));
      }
      mx = fmaxf(mx, __shfl_xor(mx, 32));
      float m2c = mx * K2;
      int defer = (m2c <= m2 + 11.0f);
      if (!__all(defer)) {
        float m2n = fmaxf(m2, m2c);
        float corr = exp2f(m2 - m2n);
        m2 = m2n; l *= corr;
#pragma unroll
        for (int t = 0; t < 4; ++t)
#pragma unroll
          for (int r = 0; r < 16; ++r) ot[t][r] *= corr;
      }
      float sum = 0.f;
#pragma unroll
      for (int r = 0; r < 16; ++r) {
        p0[r] = exp2f(__builtin_fmaf(p0[r], K2, -m2));
        p1[r] = exp2f(__builtin_fmaf(p1[r], K2, -m2));
        sum += p0[r] + p1[r];
      }
      l += sum + __shfl_xor(sum, 32);
      u32 pw0[8], pw1[8];
#pragma unroll
      for (int t = 0; t < 8; ++t) {
        pw0[t] = __builtin_bit_cast(u32, __builtin_amdgcn_cvt_pkrtz(p0[2 * t], p0[2 * t + 1]));
        pw1[t] = __builtin_bit_cast(u32, __builtin_amdgcn_cvt_pkrtz(p1[2 * t], p1[2 * t + 1]));
      }
      f16x8 pf[4];
#pragma unroll
      for (int ch = 0; ch < 2; ++ch) {
        const u32* pw = ch ? pw1 : pw0;
        u32 sx[8];
#pragma unroll
        for (int t = 0; t < 8; ++t) sx[t] = (u32)__shfl_xor((int)pw[t], 32);
        u32x4 fa = { hi ? sx[2] : pw[0], hi ? sx[3] : pw[1],
                     hi ? pw[2] : sx[0], hi ? pw[3] : sx[1] };
        u32x4 fb = { hi ? sx[6] : pw[4], hi ? sx[7] : pw[5],
                     hi ? pw[6] : sx[4], hi ? pw[7] : sx[5] };
        pf[ch * 2 + 0] = __builtin_bit_cast(f16x8, fa);
        pf[ch * 2 + 1] = __builtin_bit_cast(f16x8, fb);
      }
#pragma unroll
      for (int dt = 0; dt < 4; ++dt) {
        int d = dt * 32 + q;
#pragma unroll
        for (int f = 0; f < 4; ++f) {
          f16x8 vf = *(const f16x8*)(Vb + d * 64 + (((f * 2 + hi) ^ (q & 7)) * 8));
          ot[dt] = __builtin_amdgcn_mfma_f32_32x32x16_f16(vf, pf[f], ot[dt], 0, 0, 0);
        }
      }
    }
    buf ^= 1;
  }

  __syncthreads();
  char* scr = &KV[0][0] + w * 8192;
  float inv = 1.f / l;
#pragma unroll
  for (int dt = 0; dt < 4; ++dt) {
#pragma unroll
    for (int rg = 0; rg < 4; ++rg) {
      u32 wa = __builtin_bit_cast(u32, __builtin_amdgcn_cvt_pkrtz(ot[dt][rg * 4 + 0] * inv, ot[dt][rg * 4 + 1] * inv));
      u32 wb = __builtin_bit_cast(u32, __builtin_amdgcn_cvt_pkrtz(ot[dt][rg * 4 + 2] * inv, ot[dt][rg * 4 + 3] * inv));
      int byte = q * 256 + (((dt * 4 + rg) ^ (q & 7)) * 16) + hi * 8;
      u32* p = (u32*)(scr + byte);
      p[0] = wa; p[1] = wb;
    }
  }
  asm volatile("s_waitcnt lgkmcnt(0)" ::: "memory");
#pragma unroll
  for (int ps = 0; ps < 8; ++ps) {
    int qr = ps * 4 + (ln >> 4);
    int ck = (ln & 15) ^ (qr & 7);
    f16x8 v = *(const f16x8*)(scr + qr * 256 + ck * 16);
    *(f16x8*)(AO + (size_t)(q0c + w * 32 + qr) * HID + h * HD + (ln & 15) * 8) = v;
  }
}

extern "C" void kernel_launch(void* const* d_in, const int* in_sizes, int n_in,
                              void* d_out, int out_size, void* d_ws, size_t ws_size,
                              hipStream_t stream) {
  const float* hs = (const float*)d_in[0];
  // d_in[1] = attention_mask (pure causal; handled analytically)
  const float* wq = (const float*)d_in[2];
  const float* wk = (const float*)d_in[3];
  const float* wv = (const float*)d_in[4];
  const float* wo = (const float*)d_in[5];
  float* out = (float*)d_out;

  char* ws = (char*)d_ws;
  size_t off = 0;
  auto alloc = [&](size_t b) { char* p = ws + off; off += (b + 255) & ~(size_t)255; return p; };
  f16* Hh   = (f16*)alloc((size_t)S_LEN * HID * 2);
  f16* Wt   = (f16*)alloc((size_t)NQKV * HID * 2);
  float4* trig = (float4*)alloc((size_t)S_LEN * 64 * sizeof(float4));
  f16* Qrp  = (f16*)alloc((size_t)S_LEN * HID * 2);
  f16* Krp  = (f16*)alloc((size_t)S_LEN * KVW * 2);
  f16* Vtp  = (f16*)alloc((size_t)KVW * S_LEN * 2);
  f16* AO   = (f16*)alloc((size_t)S_LEN * HID * 2);
  f16* Wot  = (f16*)alloc((size_t)HID * HID * 2);

  // gemm8: LDS 4*16K (A halves) + 3*24K (B tiles) = 136KB
  hipFuncSetAttribute((const void*)k_gemm8,
                      hipFuncAttributeMaxDynamicSharedMemorySize, 139264);
  // gemm<1>: 8 waves 2x4, wave 128x32, BM=256 BN=128, LDS 2*32K + 4*16K = 128 KiB
  hipFuncSetAttribute((const void*)k_gemm4<1, 8, 2, 2, 4>,
                      hipFuncAttributeMaxDynamicSharedMemorySize, 131072);

  k_prep<<<45568, 256, 0, stream>>>(hs, wq, wk, wv, wo, Hh, Wt, Wot, trig);
  k_gemm8<<<dim3(NQKV / 192, S_LEN / 256), 512, 139264, stream>>>(
      Hh, Wt, Qrp, Krp, Vtp, trig);
  k_attn<<<dim3(512), 256, 0, stream>>>(Qrp, Krp, Vtp, AO);
  k_gemm4<1, 8, 2, 2, 4><<<dim3(HID / 128, S_LEN / 256), 512, 131072, stream>>>(
      AO, Wot, nullptr, nullptr, nullptr, nullptr, out);
}